// Round 4
// baseline (475.092 us; speedup 1.0000x reference)
//
#include <hip/hip_runtime.h>

#define NN 100000
#define NE 1200000
#define CH 64
#define NREL 5
#define NCLS 8
#define SLOT 64      // max in-degree tracked; deg ~ Poisson(12), P(>64) ~ 1e-30
#define BN 128       // nodes per block
#define KTOT 384     // 6*64 (root + 5 relations)
#define HPAD 66      // padded h2-stage stride (floats)

typedef _Float16 f16;
typedef _Float16 f16x4 __attribute__((ext_vector_type(4)));
typedef _Float16 f16x8 __attribute__((ext_vector_type(8)));
typedef float f32x4 __attribute__((ext_vector_type(4)));

#define RFL __builtin_amdgcn_readfirstlane

// ---- x (f32) -> f16 ----
__global__ __launch_bounds__(256) void cvt_f16_kernel(const float* __restrict__ x,
                                                      f16* __restrict__ xh) {
    int t = blockIdx.x * 256 + threadIdx.x;
    if (t >= NN * CH / 4) return;
    float4 v = reinterpret_cast<const float4*>(x)[t];
    f16x4 h = {(f16)v.x, (f16)v.y, (f16)v.z, (f16)v.w};
    *reinterpret_cast<f16x4*>(xh + (size_t)t * 4) = h;
}

// ---- build per-dst edge lists: sorted[d*SLOT+k] = src | (rel<<17) ----
__global__ __launch_bounds__(256) void scatter_kernel(const int* __restrict__ src,
                                                      const int* __restrict__ dst,
                                                      const int* __restrict__ et,
                                                      int* __restrict__ cursor,
                                                      int* __restrict__ sorted) {
    int e = blockIdx.x * 256 + threadIdx.x;
    if (e >= NE) return;
    int d = dst[e];
    int pos = atomicAdd(&cursor[d], 1);
    if (pos < SLOT) sorted[(size_t)d * SLOT + pos] = src[e] | (et[e] << 17);
}

// ---- convert weights to f16 B^T layout: Btg[layer][n][k] ----
__global__ __launch_bounds__(256) void prep_weights(const float* __restrict__ root1,
                                                    const float* __restrict__ W1,
                                                    const float* __restrict__ root2,
                                                    const float* __restrict__ W2,
                                                    f16* __restrict__ Btg) {
    int o = blockIdx.x * 256 + threadIdx.x;
    if (o >= 2 * 64 * KTOT) return;
    int layer = o / (64 * KTOT);
    int rem = o % (64 * KTOT);
    int n = rem / KTOT, k = rem % KTOT;
    const float* R = layer ? root2 : root1;
    const float* W = layer ? W2 : W1;
    float v = (k < CH) ? R[k * CH + n] : W[(size_t)(k - CH) * CH + n];
    Btg[o] = (f16)v;
}

// accumulate one edge value into the 5 relation streams (r is wave-uniform scalar)
#define ACCE(P, A0, A1, A2, A3, A4, C0, C1, C2, C3, C4, V)             \
    {                                                                  \
        int _r = (P) >> 17;                                            \
        if (_r == 0)      { A0 += (V); C0++; }                         \
        else if (_r == 1) { A1 += (V); C1++; }                         \
        else if (_r == 2) { A2 += (V); C2++; }                         \
        else if (_r == 3) { A3 += (V); C3++; }                         \
        else              { A4 += (V); C4++; }                         \
    }

// One block = 128 nodes. Phase 1: 2-node-interleaved gather of per-relation means
// into f16 A-panel in LDS. Phase 2: MFMA [128x384]x[384x64], bias in C-init.
// Epilogue: relu+f16 store (layer1) or f32 out + fused classifier (layer2).
template<bool CLS>
__global__ __launch_bounds__(1024, 4) void fused_layer(
    const f16* __restrict__ in, const f16* __restrict__ Btg,
    const float* __restrict__ bias,
    const int* __restrict__ cursor, const int* __restrict__ sorted,
    float* __restrict__ outf, f16* __restrict__ outh,
    const float* __restrict__ Wc, const float* __restrict__ bc,
    float* __restrict__ logits) {
    __shared__ f16 Bt[64 * 400];       // 51200 B  weights [n][k], 800B padded rows
    __shared__ f16 Ap[BN * 400];       // 102400 B A-panel [node][k], 800B padded rows
    __shared__ float WcL[CH * NCLS];   // 2 KB

    const int tid = threadIdx.x;
    const int wv = tid >> 6, lane = tid & 63;
    const int nb0 = blockIdx.x * BN;

    // stage weights (3072 x 16B chunks)
    for (int c = tid; c < (64 * KTOT * 2) / 16; c += 1024) {
        int n = c / 48, off = c % 48;
        *(float4*)((char*)Bt + n * 800 + off * 16) =
            *(const float4*)((const char*)Btg + (size_t)c * 16);
    }
    if (CLS) {
        for (int i = tid; i < CH * NCLS; i += 1024) WcL[i] = Wc[i];
    }

    // ---- phase 1: gather, 2 nodes interleaved per wave iteration ----
    for (int q = 0; q < 4; ++q) {
        int nlA = wv * 8 + 2 * q, nlB = nlA + 1;
        int iA = nb0 + nlA, iB = nb0 + nlB;
        bool okA = iA < NN, okB = iB < NN;
        const int* spA = sorted + (size_t)iA * SLOT;
        const int* spB = sorted + (size_t)iB * SLOT;

        float aA0 = 0, aA1 = 0, aA2 = 0, aA3 = 0, aA4 = 0;
        float aB0 = 0, aB1 = 0, aB2 = 0, aB3 = 0, aB4 = 0;
        int cA0 = 0, cA1 = 0, cA2 = 0, cA3 = 0, cA4 = 0;
        int cB0 = 0, cB1 = 0, cB2 = 0, cB3 = 0, cB4 = 0;
        int degA = 0, degB = 0;
        int4 pkA = {0, 0, 0, 0}, pkB = {0, 0, 0, 0};
        float xiA = 0.f, xiB = 0.f;
        if (okA) {
            degA = RFL(cursor[iA]); if (degA > SLOT) degA = SLOT;
            pkA = *(const int4*)spA;
            xiA = (float)in[(size_t)iA * CH + lane];
        }
        if (okB) {
            degB = RFL(cursor[iB]); if (degB > SLOT) degB = SLOT;
            pkB = *(const int4*)spB;
            xiB = (float)in[(size_t)iB * CH + lane];
        }
        int gA = degA >> 2, gB = degB >> 2;
        int G = gA > gB ? gA : gB;
        for (int g = 0; g < G; ++g) {
            bool dA = g < gA, dB = g < gB;
            int4 nxA, nxB;
            int pA0, pA1, pA2, pA3, pB0, pB1, pB2, pB3;
            float vA0, vA1, vA2, vA3, vB0, vB1, vB2, vB3;
            if (dA) {
                nxA = *(const int4*)(spA + 4 * g + 4);
                pA0 = RFL(pkA.x); pA1 = RFL(pkA.y); pA2 = RFL(pkA.z); pA3 = RFL(pkA.w);
                vA0 = (float)in[(size_t)(pA0 & 0x1FFFF) * CH + lane];
                vA1 = (float)in[(size_t)(pA1 & 0x1FFFF) * CH + lane];
                vA2 = (float)in[(size_t)(pA2 & 0x1FFFF) * CH + lane];
                vA3 = (float)in[(size_t)(pA3 & 0x1FFFF) * CH + lane];
            }
            if (dB) {
                nxB = *(const int4*)(spB + 4 * g + 4);
                pB0 = RFL(pkB.x); pB1 = RFL(pkB.y); pB2 = RFL(pkB.z); pB3 = RFL(pkB.w);
                vB0 = (float)in[(size_t)(pB0 & 0x1FFFF) * CH + lane];
                vB1 = (float)in[(size_t)(pB1 & 0x1FFFF) * CH + lane];
                vB2 = (float)in[(size_t)(pB2 & 0x1FFFF) * CH + lane];
                vB3 = (float)in[(size_t)(pB3 & 0x1FFFF) * CH + lane];
            }
            if (dA) {
                ACCE(pA0, aA0, aA1, aA2, aA3, aA4, cA0, cA1, cA2, cA3, cA4, vA0);
                ACCE(pA1, aA0, aA1, aA2, aA3, aA4, cA0, cA1, cA2, cA3, cA4, vA1);
                ACCE(pA2, aA0, aA1, aA2, aA3, aA4, cA0, cA1, cA2, cA3, cA4, vA2);
                ACCE(pA3, aA0, aA1, aA2, aA3, aA4, cA0, cA1, cA2, cA3, cA4, vA3);
                pkA = nxA;
            }
            if (dB) {
                ACCE(pB0, aB0, aB1, aB2, aB3, aB4, cB0, cB1, cB2, cB3, cB4, vB0);
                ACCE(pB1, aB0, aB1, aB2, aB3, aB4, cB0, cB1, cB2, cB3, cB4, vB1);
                ACCE(pB2, aB0, aB1, aB2, aB3, aB4, cB0, cB1, cB2, cB3, cB4, vB2);
                ACCE(pB3, aB0, aB1, aB2, aB3, aB4, cB0, cB1, cB2, cB3, cB4, vB3);
                pkB = nxB;
            }
        }
        // tails (remaining 0..3 edges already in pk)
        int remA = degA & 3, remB = degB & 3;
        if (remA > 0) { int p = RFL(pkA.x); float v = (float)in[(size_t)(p & 0x1FFFF) * CH + lane];
                        ACCE(p, aA0, aA1, aA2, aA3, aA4, cA0, cA1, cA2, cA3, cA4, v); }
        if (remA > 1) { int p = RFL(pkA.y); float v = (float)in[(size_t)(p & 0x1FFFF) * CH + lane];
                        ACCE(p, aA0, aA1, aA2, aA3, aA4, cA0, cA1, cA2, cA3, cA4, v); }
        if (remA > 2) { int p = RFL(pkA.z); float v = (float)in[(size_t)(p & 0x1FFFF) * CH + lane];
                        ACCE(p, aA0, aA1, aA2, aA3, aA4, cA0, cA1, cA2, cA3, cA4, v); }
        if (remB > 0) { int p = RFL(pkB.x); float v = (float)in[(size_t)(p & 0x1FFFF) * CH + lane];
                        ACCE(p, aB0, aB1, aB2, aB3, aB4, cB0, cB1, cB2, cB3, cB4, v); }
        if (remB > 1) { int p = RFL(pkB.y); float v = (float)in[(size_t)(p & 0x1FFFF) * CH + lane];
                        ACCE(p, aB0, aB1, aB2, aB3, aB4, cB0, cB1, cB2, cB3, cB4, v); }
        if (remB > 2) { int p = RFL(pkB.z); float v = (float)in[(size_t)(p & 0x1FFFF) * CH + lane];
                        ACCE(p, aB0, aB1, aB2, aB3, aB4, cB0, cB1, cB2, cB3, cB4, v); }

        f16* arA = (f16*)((char*)Ap + (size_t)nlA * 800);
        f16* arB = (f16*)((char*)Ap + (size_t)nlB * 800);
        arA[0 * CH + lane] = (f16)xiA;
        arA[1 * CH + lane] = (f16)(aA0 * (1.0f / fmaxf((float)cA0, 1.0f)));
        arA[2 * CH + lane] = (f16)(aA1 * (1.0f / fmaxf((float)cA1, 1.0f)));
        arA[3 * CH + lane] = (f16)(aA2 * (1.0f / fmaxf((float)cA2, 1.0f)));
        arA[4 * CH + lane] = (f16)(aA3 * (1.0f / fmaxf((float)cA3, 1.0f)));
        arA[5 * CH + lane] = (f16)(aA4 * (1.0f / fmaxf((float)cA4, 1.0f)));
        arB[0 * CH + lane] = (f16)xiB;
        arB[1 * CH + lane] = (f16)(aB0 * (1.0f / fmaxf((float)cB0, 1.0f)));
        arB[2 * CH + lane] = (f16)(aB1 * (1.0f / fmaxf((float)cB1, 1.0f)));
        arB[3 * CH + lane] = (f16)(aB2 * (1.0f / fmaxf((float)cB2, 1.0f)));
        arB[4 * CH + lane] = (f16)(aB3 * (1.0f / fmaxf((float)cB3, 1.0f)));
        arB[5 * CH + lane] = (f16)(aB4 * (1.0f / fmaxf((float)cB4, 1.0f)));
    }
    __syncthreads();

    // ---- phase 2: MFMA. wave w: M-tile tm = w>>1, N-tiles tn, tn+1 ----
    const int tm = wv >> 1;
    const int tn = (wv & 1) * 2;
    const int col = lane & 15, lg = lane >> 4;
    float bv0 = bias[tn * 16 + col];
    float bv1 = bias[tn * 16 + 16 + col];
    f32x4 acc0 = {bv0, bv0, bv0, bv0};
    f32x4 acc1 = {bv1, bv1, bv1, bv1};
    const char* Ab = (const char*)Ap + (tm * 16 + col) * 800 + lg * 16;
    const char* Bb0 = (const char*)Bt + (tn * 16 + col) * 800 + lg * 16;
    const char* Bb1 = Bb0 + 16 * 800;
#pragma unroll
    for (int k = 0; k < KTOT / 32; ++k) {
        f16x8 af = *(const f16x8*)(Ab + k * 64);
        f16x8 bf0 = *(const f16x8*)(Bb0 + k * 64);
        f16x8 bf1 = *(const f16x8*)(Bb1 + k * 64);
        acc0 = __builtin_amdgcn_mfma_f32_16x16x32_f16(af, bf0, acc0, 0, 0, 0);
        acc1 = __builtin_amdgcn_mfma_f32_16x16x32_f16(af, bf1, acc1, 0, 0, 0);
    }

    if (!CLS) {
#pragma unroll
        for (int r = 0; r < 4; ++r) {
            int node = nb0 + tm * 16 + lg * 4 + r;
            if (node < NN) {
                outh[(size_t)node * CH + tn * 16 + col] = (f16)fmaxf(acc0[r], 0.f);
                outh[(size_t)node * CH + (tn + 1) * 16 + col] = (f16)fmaxf(acc1[r], 0.f);
            }
        }
    } else {
        __syncthreads();  // Ap reads done; reuse as h-stage
        float* hst = (float*)Ap;  // [BN][HPAD]
        float bcr[NCLS];
#pragma unroll
        for (int c = 0; c < NCLS; ++c) bcr[c] = bc[c];
#pragma unroll
        for (int r = 0; r < 4; ++r) {
            int nloc = tm * 16 + lg * 4 + r;
            int node = nb0 + nloc;
            hst[nloc * HPAD + tn * 16 + col] = acc0[r];
            hst[nloc * HPAD + (tn + 1) * 16 + col] = acc1[r];
            if (node < NN) {
                outf[(size_t)node * CH + tn * 16 + col] = acc0[r];
                outf[(size_t)node * CH + (tn + 1) * 16 + col] = acc1[r];
            }
        }
        __syncthreads();
        for (int q = 0; q < 8; ++q) {
            int nl = wv * 8 + q;
            int i = nb0 + nl;
            if (i >= NN) continue;
            float v = hst[nl * HPAD + lane];
            float p[NCLS];
#pragma unroll
            for (int c = 0; c < NCLS; ++c) p[c] = v * WcL[lane * NCLS + c];
#pragma unroll
            for (int off = 32; off > 0; off >>= 1) {
#pragma unroll
                for (int c = 0; c < NCLS; ++c) p[c] += __shfl_xor(p[c], off);
            }
            if (lane == 0) {
                float4 lo = make_float4(p[0] + bcr[0], p[1] + bcr[1], p[2] + bcr[2], p[3] + bcr[3]);
                float4 hi = make_float4(p[4] + bcr[4], p[5] + bcr[5], p[6] + bcr[6], p[7] + bcr[7]);
                *reinterpret_cast<float4*>(&logits[(size_t)i * NCLS]) = lo;
                *reinterpret_cast<float4*>(&logits[(size_t)i * NCLS + 4]) = hi;
            }
        }
    }
}

extern "C" void kernel_launch(void* const* d_in, const int* in_sizes, int n_in,
                              void* d_out, int out_size, void* d_ws, size_t ws_size,
                              hipStream_t stream) {
    const float* x     = (const float*)d_in[0];
    const int*   ei    = (const int*)d_in[1];
    const int*   et    = (const int*)d_in[2];
    const float* W1    = (const float*)d_in[3];
    const float* root1 = (const float*)d_in[4];
    const float* b1    = (const float*)d_in[5];
    const float* W2    = (const float*)d_in[6];
    const float* root2 = (const float*)d_in[7];
    const float* b2    = (const float*)d_in[8];
    const float* Wc    = (const float*)d_in[9];
    const float* bc    = (const float*)d_in[10];
    const int* src = ei;
    const int* dst = ei + NE;

    float* h2     = (float*)d_out;            // [NN][CH]
    float* logits = h2 + (size_t)NN * CH;     // [NN][NCLS]

    int* cursor = (int*)d_ws;                                   // [NN]
    int* sorted = cursor + NN;                                  // [NN][SLOT] + 16 slack
    f16* h1h    = (f16*)(sorted + (size_t)NN * SLOT + 16);      // [NN][CH]
    f16* xh     = h1h + (size_t)NN * CH;                        // [NN][CH]
    f16* Btg    = xh + (size_t)NN * CH;                         // [2][64][KTOT]

    hipMemsetAsync(cursor, 0, (size_t)NN * 4, stream);
    cvt_f16_kernel<<<(NN * CH / 4 + 255) / 256, 256, 0, stream>>>(x, xh);
    scatter_kernel<<<(NE + 255) / 256, 256, 0, stream>>>(src, dst, et, cursor, sorted);
    prep_weights<<<(2 * 64 * KTOT + 255) / 256, 256, 0, stream>>>(root1, W1, root2, W2, Btg);

    int nBlk = (NN + BN - 1) / BN;  // 782
    fused_layer<false><<<nBlk, 1024, 0, stream>>>(
        xh, Btg, b1, cursor, sorted, nullptr, h1h, nullptr, nullptr, nullptr);
    fused_layer<true><<<nBlk, 1024, 0, stream>>>(
        h1h, Btg + (size_t)64 * KTOT, b2, cursor, sorted, h2, nullptr, Wc, bc, logits);
}